// Round 5
// baseline (7037.279 us; speedup 1.0000x reference)
//
#include <hip/hip_runtime.h>
#include <cstdint>

// Bidirectional masked LSTM encoder, B=64, T=512, E=256, U=512, G=2048.
// R8: STEP-PER-LAUNCH redesign. R4-R7 all aborted (~6s SIGABRT), including
// a byte-identical copy of the round-0 PASS -> the persistent-kernel spin
// protocol's liveness (requires 64 co-resident WGs) is not trustworthy on
// this harness anymore. This version's only sync primitive is the kernel
// boundary: 512 sequential lstm_step launches (fwd+bwd fused per launch),
// no atomics, no spin, no sc0/sc1 asm, nothing inter-block -> cannot hang
// under ANY scheduling/sharing/replay. Math is R3's proven structure:
// WG=(dir,cg) owns 16 units; MFMA 16x16x32 bf16; LDS gate regroup; f32
// masked carry. Weights pre-converted ONCE to fragment-ordered bf16 so the
// per-step weight reload is pure coalesced 16B/lane from L2/L3.

#define B_ 64
#define T_ 512
#define E_ 256

typedef __attribute__((ext_vector_type(8))) short bf16x8;
typedef __attribute__((ext_vector_type(4))) float f32x4;

__device__ __forceinline__ unsigned short f2bf(float x) {
  unsigned u = __float_as_uint(x);
  u += 0x7FFFu + ((u >> 16) & 1u);      // round-to-nearest-even
  return (unsigned short)(u >> 16);
}
__device__ __forceinline__ float sigm(float x) { return 1.0f / (1.0f + __expf(-x)); }
__device__ __forceinline__ float tanh_(float x) { return 1.0f - 2.0f / (__expf(2.0f * x) + 1.0f); }

// Gather + f32->bf16 cast of the embedded sequence into [t][b][e] layout.
__global__ void prep_kernel(const int* __restrict__ enc, const float* __restrict__ emb,
                            unsigned short* __restrict__ o) {
  const int bi = blockIdx.x;
  const int t = bi >> 6, b = bi & 63;
  const int tok = enc[b * T_ + t];
  float4 v = ((const float4*)(emb + (size_t)tok * E_))[threadIdx.x];
  ushort4 w;
  w.x = f2bf(v.x); w.y = f2bf(v.y); w.z = f2bf(v.z); w.w = f2bf(v.w);
  ((ushort4*)(o + (size_t)t * (B_ * E_) + b * E_))[threadIdx.x] = w;
}

// One-time weight repack: f32 [K][2048] -> fragment-ordered bf16 so each
// step-kernel thread loads its MFMA B-frag as one contiguous bf16x8.
// Uq[d][cg][nh][ks(16)][ns][lane][8], Wq[d][cg][nh][ks(8)][ns][lane][8].
// grid = 2d * 32cg * 2nh * 24kk * 2ns = 6144 blocks, 64 threads.
__global__ void prep_w(const float* __restrict__ Wf, const float* __restrict__ Uf,
                       const float* __restrict__ Wb, const float* __restrict__ Ub,
                       unsigned short* __restrict__ Uq, unsigned short* __restrict__ Wq) {
  int bi = blockIdx.x;
  const int ns = bi & 1; bi >>= 1;
  const int kk = bi % 24; bi /= 24;
  const int nh = bi & 1; bi >>= 1;
  const int cg = bi & 31; bi >>= 5;
  const int d = bi;
  const int lane = threadIdx.x;
  const int l15 = lane & 15, l4 = lane >> 4;
  const bool isU = (kk < 16);
  const float* src = isU ? (d ? Ub : Uf) : (d ? Wb : Wf);
  const int ks = isU ? kk : (kk - 16);
  const int col = (nh * 2 + ns) * 512 + cg * 16 + l15;
  const int row0 = ks * 32 + l4 * 8;
  bf16x8 f;
#pragma unroll
  for (int i = 0; i < 8; ++i) f[i] = (short)f2bf(src[(size_t)(row0 + i) * 2048 + col]);
  unsigned short* dst = isU
    ? Uq + ((size_t)(((d * 32 + cg) * 2 + nh) * 16 + ks) * 2 + ns) * 512 + lane * 8
    : Wq + ((size_t)(((d * 32 + cg) * 2 + nh) * 8 + ks) * 2 + ns) * 512 + lane * 8;
  *(bf16x8*)dst = f;
}

// One time step, both directions. 64 blocks x 256 threads.
// block = (dir d = bid>>5, col-group cg = bid&31): units [cg*16, cg*16+16).
// Wave (of 4) = (mh = batch-half, nh = gate-pair). All state in global:
//   Hbf  [parity][d][b][512u] bf16  (MFMA A-source, double-buffered)
//   Hf32 [d][b][512u] f32           (exact masked-carry h, own slice only)
//   Cst  [d][b][512u] f32           (cell state, own slice only)
__global__ __launch_bounds__(256, 1)
void lstm_step(const int s, const int* __restrict__ enc, const unsigned short* __restrict__ embq,
               const unsigned short* __restrict__ Uq, const unsigned short* __restrict__ Wq,
               const float* __restrict__ bfv, const float* __restrict__ bbv,
               unsigned short* __restrict__ Hbf, float* __restrict__ Hf32,
               float* __restrict__ Cst, float* __restrict__ out) {
  const int tid = threadIdx.x;
  const int lane = tid & 63;
  const int wave = tid >> 6;
  const int mh = wave & 1, nh = wave >> 1;
  const int l15 = lane & 15, l4 = lane >> 4;
  const int d = blockIdx.x >> 5;
  const int cg = blockIdx.x & 31;
  const int u0 = cg * 16;
  const int t = d ? (T_ - 1 - s) : s;

  __shared__ float Z[64][68];   // gate-regroup exchange, +4 pad to spread banks

  // ---- weight frags: coalesced 16B/lane from the repacked L2/L3-hot buffers ----
  const unsigned short* ub = Uq + ((size_t)((d * 32 + cg) * 2 + nh)) * (16 * 2 * 512);
  const unsigned short* wb = Wq + ((size_t)((d * 32 + cg) * 2 + nh)) * (8 * 2 * 512);
  bf16x8 u_frag[16][2];
#pragma unroll
  for (int ks = 0; ks < 16; ++ks)
#pragma unroll
    for (int ns = 0; ns < 2; ++ns)
      u_frag[ks][ns] = *(const bf16x8*)(ub + (size_t)(ks * 2 + ns) * 512 + lane * 8);
  bf16x8 w_frag[8][2];
#pragma unroll
  for (int ks = 0; ks < 8; ++ks)
#pragma unroll
    for (int ns = 0; ns < 2; ++ns)
      w_frag[ks][ns] = *(const bf16x8*)(wb + (size_t)(ks * 2 + ns) * 512 + lane * 8);

  // ---- emb A-frags + mask for this step ----
  bf16x8 apf[8][2];
  {
    const unsigned short* eT = embq + (size_t)t * (B_ * E_);
#pragma unroll
    for (int ks = 0; ks < 8; ++ks)
#pragma unroll
      for (int ms = 0; ms < 2; ++ms) {
        const int b = mh * 32 + ms * 16 + l15;
        apf[ks][ms] = *(const bf16x8*)(eT + b * E_ + ks * 32 + l4 * 8);
      }
  }
  const int ej = tid & 15;
  const int ebg = tid >> 4;
  int mpf[4];
#pragma unroll
  for (int r = 0; r < 4; ++r) mpf[r] = enc[(ebg * 4 + r) * T_ + t];

  f32x4 acc[2][2];
#pragma unroll
  for (int ms = 0; ms < 2; ++ms)
#pragma unroll
    for (int ns = 0; ns < 2; ++ns) acc[ms][ns] = (f32x4)0.0f;

  // ---- x-part: emb @ W ----
#pragma unroll
  for (int ks = 0; ks < 8; ++ks)
#pragma unroll
    for (int ms = 0; ms < 2; ++ms)
#pragma unroll
      for (int ns = 0; ns < 2; ++ns)
        acc[ms][ns] = __builtin_amdgcn_mfma_f32_16x16x32_bf16(apf[ks][ms], w_frag[ks][ns],
                                                              acc[ms][ns], 0, 0, 0);

  // ---- h-part: H(s) @ U. Previous launch's writes are visible (kernel
  //      boundary = full coherence point): plain loads, no flags. ----
  if (s > 0) {
    const unsigned short* Hrd = Hbf + ((size_t)((s & 1) * 2 + d)) * (B_ * 512);
    bf16x8 ha[16][2];
#pragma unroll
    for (int ks = 0; ks < 16; ++ks)
#pragma unroll
      for (int ms = 0; ms < 2; ++ms) {
        const int b = mh * 32 + ms * 16 + l15;
        ha[ks][ms] = *(const bf16x8*)(Hrd + (size_t)b * 512 + ks * 32 + l4 * 8);
      }
#pragma unroll
    for (int ks = 0; ks < 16; ++ks) {
      acc[0][0] = __builtin_amdgcn_mfma_f32_16x16x32_bf16(ha[ks][0], u_frag[ks][0], acc[0][0], 0, 0, 0);
      acc[0][1] = __builtin_amdgcn_mfma_f32_16x16x32_bf16(ha[ks][0], u_frag[ks][1], acc[0][1], 0, 0, 0);
      acc[1][0] = __builtin_amdgcn_mfma_f32_16x16x32_bf16(ha[ks][1], u_frag[ks][0], acc[1][0], 0, 0, 0);
      acc[1][1] = __builtin_amdgcn_mfma_f32_16x16x32_bf16(ha[ks][1], u_frag[ks][1], acc[1][1], 0, 0, 0);
    }
  }

  // ---- regroup gates per (b,u) via LDS (C/D layout: col=lane&15, row=quad*4+reg) ----
#pragma unroll
  for (int ms = 0; ms < 2; ++ms)
#pragma unroll
    for (int ns = 0; ns < 2; ++ns)
#pragma unroll
      for (int r = 0; r < 4; ++r)
        Z[mh * 32 + ms * 16 + l4 * 4 + r][nh * 32 + ns * 16 + l15] = acc[ms][ns][r];
  __syncthreads();

  // ---- elementwise LSTM cell + masked carry; state round-trips via global ----
  const float* bd = d ? bbv : bfv;
  float bias[4];
#pragma unroll
  for (int g = 0; g < 4; ++g) bias[g] = bd[g * 512 + u0 + ej];

  float* Hf = Hf32 + (size_t)d * (B_ * 512);
  float* Cf = Cst + (size_t)d * (B_ * 512);
  unsigned short* Hwr = Hbf + ((size_t)(((s + 1) & 1) * 2 + d)) * (B_ * 512);
  const bool last = (s == T_ - 1);
#pragma unroll
  for (int r = 0; r < 4; ++r) {
    const int b = ebg * 4 + r;
    const size_t si = (size_t)b * 512 + u0 + ej;
    float zi = Z[b][ej] + bias[0];
    float zf = Z[b][16 + ej] + bias[1];
    float zg = Z[b][32 + ej] + bias[2];
    float zo = Z[b][48 + ej] + bias[3];
    float ig = sigm(zi), fg = sigm(zf), gg = tanh_(zg), og = sigm(zo);
    float hp = Hf[si], cp = Cf[si];
    float cn = fg * cp + ig * gg;
    float hn = og * tanh_(cn);
    const bool m = (mpf[r] != 0);
    float hv = m ? hn : hp;
    float cv = m ? cn : cp;
    Hf[si] = hv;
    Cf[si] = cv;
    Hwr[si] = f2bf(hv);
    out[((size_t)b * T_ + t) * 1024 + d * 512 + u0 + ej] = hv;
    if (last) {
      out[33554432u + (size_t)b * 1024 + d * 512 + u0 + ej] = hv;
      out[33619968u + (size_t)b * 1024 + d * 512 + u0 + ej] = cv;
    }
  }
}

extern "C" void kernel_launch(void* const* d_in, const int* in_sizes, int n_in,
                              void* d_out, int out_size, void* d_ws, size_t ws_size,
                              hipStream_t stream) {
  const int* enc = (const int*)d_in[0];
  const float* emb = (const float*)d_in[1];
  const float* Wf = (const float*)d_in[2];
  const float* Uf = (const float*)d_in[3];
  const float* bf = (const float*)d_in[4];
  const float* Wb = (const float*)d_in[5];
  const float* Ub = (const float*)d_in[6];
  const float* bb = (const float*)d_in[7];
  float* out = (float*)d_out;
  char* ws = (char*)d_ws;

  // workspace layout (22.75 MiB total):
  unsigned short* embq = (unsigned short*)ws;                  // [T][B][E] bf16, 16 MiB
  unsigned short* Uq  = (unsigned short*)(ws + 16777216u);     // frag-ordered U, 4 MiB
  unsigned short* Wq  = (unsigned short*)(ws + 20971520u);     // frag-ordered W, 2 MiB
  unsigned short* Hbf = (unsigned short*)(ws + 23068672u);     // [2 par][2 d][64][512] bf16, 256 KiB
  float* Hf32 = (float*)(ws + 23330816u);                      // [2 d][64][512] f32, 256 KiB
  float* Cst  = (float*)(ws + 23592960u);                      // [2 d][64][512] f32, 256 KiB

  // zero h/c state (h==0, c==0 at s=0; Hbf parity-0 never read but cheap)
  hipMemsetAsync(ws + 23068672u, 0, 786432u, stream);
  prep_kernel<<<32768, 64, 0, stream>>>(enc, emb, embq);
  prep_w<<<6144, 64, 0, stream>>>(Wf, Uf, Wb, Ub, Uq, Wq);
  for (int s = 0; s < 512; ++s)
    lstm_step<<<64, 256, 0, stream>>>(s, enc, embq, Uq, Wq, bf, bb, Hbf, Hf32, Cst, out);
}

// Round 6
// 4556.441 us; speedup vs baseline: 1.5445x; 1.5445x over previous
//
#include <hip/hip_runtime.h>
#include <cstdint>

// Bidirectional masked LSTM encoder, B=64, T=512, E=256, U=512, G=2048.
// R9: PIPELINED STEP-DAG. R4-R7 aborts were ~6-10s = amdgpu job-timeout
// resetting a hung queue (even for the byte-identical R0 pass) -> the
// persistent 64-WG all-to-all spin's co-residency premise is dead. R8
// (step-per-launch) passed but pays 512 launch gaps + full weight reload
// per step (13.7 us/step). R9 keeps step-granular blocks but puts ALL
// 512x64 step-blocks in ONE grid: block (s,d,cg) waits ONLY on step s-1
// blocks (strictly lower blockIdx). Under FIFO dispatch this is live with
// even ONE free CU slot (predecessors never wait on successors) -- no
// co-residency assumption. ~4 steps pipeline concurrently (1 block/CU),
// hiding weight/emb reloads behind the ~3us/step dependency chain and
// removing all launch gaps. H is stored PER STEP (no slot reuse -> no
// ring races, replay-safe). Cross-block data via sc0 sc1 (R3-proven);
// flags via __hip_atomic agent scope (R3-proven); s_sleep backoff in poll.
// Runtime ws_size check: < 87 MB falls back to verbatim-R8 step-per-launch.

#define B_ 64
#define T_ 512
#define E_ 256

typedef __attribute__((ext_vector_type(8))) short bf16x8;
typedef __attribute__((ext_vector_type(4))) float f32x4;

__device__ __forceinline__ unsigned short f2bf(float x) {
  unsigned u = __float_as_uint(x);
  u += 0x7FFFu + ((u >> 16) & 1u);      // round-to-nearest-even
  return (unsigned short)(u >> 16);
}
__device__ __forceinline__ float sigm(float x) { return 1.0f / (1.0f + __expf(-x)); }
__device__ __forceinline__ float tanh_(float x) { return 1.0f - 2.0f / (__expf(2.0f * x) + 1.0f); }

// Gather + f32->bf16 cast of the embedded sequence into [t][b][e] layout.
__global__ void prep_kernel(const int* __restrict__ enc, const float* __restrict__ emb,
                            unsigned short* __restrict__ o) {
  const int bi = blockIdx.x;
  const int t = bi >> 6, b = bi & 63;
  const int tok = enc[b * T_ + t];
  float4 v = ((const float4*)(emb + (size_t)tok * E_))[threadIdx.x];
  ushort4 w;
  w.x = f2bf(v.x); w.y = f2bf(v.y); w.z = f2bf(v.z); w.w = f2bf(v.w);
  ((ushort4*)(o + (size_t)t * (B_ * E_) + b * E_))[threadIdx.x] = w;
}

// One-time weight repack: f32 [K][2048] -> fragment-ordered bf16 (per-thread
// contiguous bf16x8 MFMA B-frags). Layouts as R8 (verified).
__global__ void prep_w(const float* __restrict__ Wf, const float* __restrict__ Uf,
                       const float* __restrict__ Wb, const float* __restrict__ Ub,
                       unsigned short* __restrict__ Uq, unsigned short* __restrict__ Wq) {
  int bi = blockIdx.x;
  const int ns = bi & 1; bi >>= 1;
  const int kk = bi % 24; bi /= 24;
  const int nh = bi & 1; bi >>= 1;
  const int cg = bi & 31; bi >>= 5;
  const int d = bi;
  const int lane = threadIdx.x;
  const int l15 = lane & 15, l4 = lane >> 4;
  const bool isU = (kk < 16);
  const float* src = isU ? (d ? Ub : Uf) : (d ? Wb : Wf);
  const int ks = isU ? kk : (kk - 16);
  const int col = (nh * 2 + ns) * 512 + cg * 16 + l15;
  const int row0 = ks * 32 + l4 * 8;
  bf16x8 f;
#pragma unroll
  for (int i = 0; i < 8; ++i) f[i] = (short)f2bf(src[(size_t)(row0 + i) * 2048 + col]);
  unsigned short* dst = isU
    ? Uq + ((size_t)(((d * 32 + cg) * 2 + nh) * 16 + ks) * 2 + ns) * 512 + lane * 8
    : Wq + ((size_t)(((d * 32 + cg) * 2 + nh) * 8 + ks) * 2 + ns) * 512 + lane * 8;
  *(bf16x8*)dst = f;
}

// ---------------- R9 primary: pipelined step-DAG, one grid ----------------
// grid 32768 = 512 steps x 64 (d,cg) blocks. Block (s,d,cg) depends only on
// step s-1 blocks (lower blockIdx). Hst[s] is written once, read once.
__global__ __launch_bounds__(256, 1)
void lstm_dag(const int* __restrict__ enc, const unsigned short* __restrict__ embq,
              const unsigned short* __restrict__ Uq, const unsigned short* __restrict__ Wq,
              const float* __restrict__ bfv, const float* __restrict__ bbv,
              unsigned short* __restrict__ Hst, float* __restrict__ Hf32,
              float* __restrict__ Cst, int* __restrict__ flg, float* __restrict__ out) {
  const int s = blockIdx.x >> 6;
  const int inner = blockIdx.x & 63;
  const int d = inner >> 5;
  const int cg = inner & 31;
  const int tid = threadIdx.x;
  const int lane = tid & 63;
  const int wave = tid >> 6;
  const int mh = wave & 1, nh = wave >> 1;
  const int l15 = lane & 15, l4 = lane >> 4;
  const int u0 = cg * 16;
  const int t = d ? (T_ - 1 - s) : s;

  __shared__ float Z[64][68];

  // ---- weight frags (coalesced 16B/lane, L2-hot after warmup) ----
  const unsigned short* ub = Uq + ((size_t)((d * 32 + cg) * 2 + nh)) * (16 * 2 * 512);
  const unsigned short* wb = Wq + ((size_t)((d * 32 + cg) * 2 + nh)) * (8 * 2 * 512);
  bf16x8 u_frag[16][2];
#pragma unroll
  for (int ks = 0; ks < 16; ++ks)
#pragma unroll
    for (int ns = 0; ns < 2; ++ns)
      u_frag[ks][ns] = *(const bf16x8*)(ub + (size_t)(ks * 2 + ns) * 512 + lane * 8);
  bf16x8 w_frag[8][2];
#pragma unroll
  for (int ks = 0; ks < 8; ++ks)
#pragma unroll
    for (int ns = 0; ns < 2; ++ns)
      w_frag[ks][ns] = *(const bf16x8*)(wb + (size_t)(ks * 2 + ns) * 512 + lane * 8);

  // ---- emb A-frags + mask ----
  bf16x8 apf[8][2];
  {
    const unsigned short* eT = embq + (size_t)t * (B_ * E_);
#pragma unroll
    for (int ks = 0; ks < 8; ++ks)
#pragma unroll
      for (int ms = 0; ms < 2; ++ms) {
        const int b = mh * 32 + ms * 16 + l15;
        apf[ks][ms] = *(const bf16x8*)(eT + b * E_ + ks * 32 + l4 * 8);
      }
  }
  const int ej = tid & 15;
  const int ebg = tid >> 4;
  int mpf[4];
#pragma unroll
  for (int r = 0; r < 4; ++r) mpf[r] = enc[(ebg * 4 + r) * T_ + t];

  f32x4 acc[2][2];
#pragma unroll
  for (int ms = 0; ms < 2; ++ms)
#pragma unroll
    for (int ns = 0; ns < 2; ++ns) acc[ms][ns] = (f32x4)0.0f;

  // ---- x-part: emb @ W (independent of predecessors: before the wait) ----
#pragma unroll
  for (int ks = 0; ks < 8; ++ks)
#pragma unroll
    for (int ms = 0; ms < 2; ++ms)
#pragma unroll
      for (int ns = 0; ns < 2; ++ns)
        acc[ms][ns] = __builtin_amdgcn_mfma_f32_16x16x32_bf16(apf[ks][ms], w_frag[ks][ns],
                                                              acc[ms][ns], 0, 0, 0);

  float hpv[4] = {0.f, 0.f, 0.f, 0.f}, cpv[4] = {0.f, 0.f, 0.f, 0.f};
  float* Hf = Hf32 + (size_t)d * (B_ * 512);
  float* Cf = Cst + (size_t)d * (B_ * 512);

  if (s > 0) {
    // ---- wait: all 32 (d,cg') blocks of step s-1 have published ----
    int* fp = flg + ((size_t)s * 2 + d) * 32;
    {
      int v; bool first = true;
      do {
        if (!first) __builtin_amdgcn_s_sleep(2);
        first = false;
        v = __hip_atomic_load(fp + (lane & 31), __ATOMIC_RELAXED, __HIP_MEMORY_SCOPE_AGENT);
      } while (__ballot(v == 0) != 0ull);
    }

    // ---- own-chain f32 state (ordered by own cg's flag above) ----
#pragma unroll
    for (int r = 0; r < 4; ++r) {
      const size_t si = (size_t)(ebg * 4 + r) * 512 + u0 + ej;
      hpv[r] = __hip_atomic_load(&Hf[si], __ATOMIC_RELAXED, __HIP_MEMORY_SCOPE_AGENT);
      cpv[r] = __hip_atomic_load(&Cf[si], __ATOMIC_RELAXED, __HIP_MEMORY_SCOPE_AGENT);
    }

    // ---- h-part: H(s) @ U, sc0 sc1 LLC loads (one asm block, single wait)
    // Hst[s] layout [d][b][512u]: lane byte base = b*1024 + l4*16, ks -> +64B
    bf16x8 ha[16][2];
    {
      const char* hb0 = (const char*)(Hst + ((size_t)s * 2 + d) * 32768)
                        + (mh * 32 + l15) * 1024 + l4 * 16;
      const char* hb1 = hb0 + 16384;   // ms=1: +16 batches
      asm volatile(
        "global_load_dwordx4 %0, %32, off offset:0 sc0 sc1\n\t"
        "global_load_dwordx4 %1, %32, off offset:64 sc0 sc1\n\t"
        "global_load_dwordx4 %2, %32, off offset:128 sc0 sc1\n\t"
        "global_load_dwordx4 %3, %32, off offset:192 sc0 sc1\n\t"
        "global_load_dwordx4 %4, %32, off offset:256 sc0 sc1\n\t"
        "global_load_dwordx4 %5, %32, off offset:320 sc0 sc1\n\t"
        "global_load_dwordx4 %6, %32, off offset:384 sc0 sc1\n\t"
        "global_load_dwordx4 %7, %32, off offset:448 sc0 sc1\n\t"
        "global_load_dwordx4 %8, %32, off offset:512 sc0 sc1\n\t"
        "global_load_dwordx4 %9, %32, off offset:576 sc0 sc1\n\t"
        "global_load_dwordx4 %10, %32, off offset:640 sc0 sc1\n\t"
        "global_load_dwordx4 %11, %32, off offset:704 sc0 sc1\n\t"
        "global_load_dwordx4 %12, %32, off offset:768 sc0 sc1\n\t"
        "global_load_dwordx4 %13, %32, off offset:832 sc0 sc1\n\t"
        "global_load_dwordx4 %14, %32, off offset:896 sc0 sc1\n\t"
        "global_load_dwordx4 %15, %32, off offset:960 sc0 sc1\n\t"
        "global_load_dwordx4 %16, %33, off offset:0 sc0 sc1\n\t"
        "global_load_dwordx4 %17, %33, off offset:64 sc0 sc1\n\t"
        "global_load_dwordx4 %18, %33, off offset:128 sc0 sc1\n\t"
        "global_load_dwordx4 %19, %33, off offset:192 sc0 sc1\n\t"
        "global_load_dwordx4 %20, %33, off offset:256 sc0 sc1\n\t"
        "global_load_dwordx4 %21, %33, off offset:320 sc0 sc1\n\t"
        "global_load_dwordx4 %22, %33, off offset:384 sc0 sc1\n\t"
        "global_load_dwordx4 %23, %33, off offset:448 sc0 sc1\n\t"
        "global_load_dwordx4 %24, %33, off offset:512 sc0 sc1\n\t"
        "global_load_dwordx4 %25, %33, off offset:576 sc0 sc1\n\t"
        "global_load_dwordx4 %26, %33, off offset:640 sc0 sc1\n\t"
        "global_load_dwordx4 %27, %33, off offset:704 sc0 sc1\n\t"
        "global_load_dwordx4 %28, %33, off offset:768 sc0 sc1\n\t"
        "global_load_dwordx4 %29, %33, off offset:832 sc0 sc1\n\t"
        "global_load_dwordx4 %30, %33, off offset:896 sc0 sc1\n\t"
        "global_load_dwordx4 %31, %33, off offset:960 sc0 sc1\n\t"
        "s_waitcnt vmcnt(0)"
        : "=v"(ha[0][0]), "=v"(ha[1][0]), "=v"(ha[2][0]), "=v"(ha[3][0]),
          "=v"(ha[4][0]), "=v"(ha[5][0]), "=v"(ha[6][0]), "=v"(ha[7][0]),
          "=v"(ha[8][0]), "=v"(ha[9][0]), "=v"(ha[10][0]), "=v"(ha[11][0]),
          "=v"(ha[12][0]), "=v"(ha[13][0]), "=v"(ha[14][0]), "=v"(ha[15][0]),
          "=v"(ha[0][1]), "=v"(ha[1][1]), "=v"(ha[2][1]), "=v"(ha[3][1]),
          "=v"(ha[4][1]), "=v"(ha[5][1]), "=v"(ha[6][1]), "=v"(ha[7][1]),
          "=v"(ha[8][1]), "=v"(ha[9][1]), "=v"(ha[10][1]), "=v"(ha[11][1]),
          "=v"(ha[12][1]), "=v"(ha[13][1]), "=v"(ha[14][1]), "=v"(ha[15][1])
        : "v"(hb0), "v"(hb1)
        : "memory");
    }
#pragma unroll
    for (int ks = 0; ks < 16; ++ks) {
      acc[0][0] = __builtin_amdgcn_mfma_f32_16x16x32_bf16(ha[ks][0], u_frag[ks][0], acc[0][0], 0, 0, 0);
      acc[0][1] = __builtin_amdgcn_mfma_f32_16x16x32_bf16(ha[ks][0], u_frag[ks][1], acc[0][1], 0, 0, 0);
      acc[1][0] = __builtin_amdgcn_mfma_f32_16x16x32_bf16(ha[ks][1], u_frag[ks][0], acc[1][0], 0, 0, 0);
      acc[1][1] = __builtin_amdgcn_mfma_f32_16x16x32_bf16(ha[ks][1], u_frag[ks][1], acc[1][1], 0, 0, 0);
    }
  }

  // ---- regroup gates per (b,u) via LDS ----
#pragma unroll
  for (int ms = 0; ms < 2; ++ms)
#pragma unroll
    for (int ns = 0; ns < 2; ++ns)
#pragma unroll
      for (int r = 0; r < 4; ++r)
        Z[mh * 32 + ms * 16 + l4 * 4 + r][nh * 32 + ns * 16 + l15] = acc[ms][ns][r];
  __syncthreads();

  // ---- cell + masked carry; state stores (agent scope, drained by the
  //      publish-asm vmcnt / __syncthreads before the flag) ----
  const float* bd = d ? bbv : bfv;
  float bias[4];
#pragma unroll
  for (int g = 0; g < 4; ++g) bias[g] = bd[g * 512 + u0 + ej];

  float hvv[4], cvv[4];
  unsigned hu[4];
#pragma unroll
  for (int r = 0; r < 4; ++r) {
    const int b = ebg * 4 + r;
    const size_t si = (size_t)b * 512 + u0 + ej;
    float zi = Z[b][ej] + bias[0];
    float zf = Z[b][16 + ej] + bias[1];
    float zg = Z[b][32 + ej] + bias[2];
    float zo = Z[b][48 + ej] + bias[3];
    float ig = sigm(zi), fg = sigm(zf), gg = tanh_(zg), og = sigm(zo);
    float cn = fg * cpv[r] + ig * gg;
    float hn = og * tanh_(cn);
    const bool m = (mpf[r] != 0);
    hvv[r] = m ? hn : hpv[r];
    cvv[r] = m ? cn : cpv[r];
    hu[r] = (unsigned)f2bf(hvv[r]);
    __hip_atomic_store(&Hf[si], hvv[r], __ATOMIC_RELAXED, __HIP_MEMORY_SCOPE_AGENT);
    __hip_atomic_store(&Cf[si], cvv[r], __ATOMIC_RELAXED, __HIP_MEMORY_SCOPE_AGENT);
  }

  // ---- publish H(s+1) (sc0 sc1 write-through, drained) ----
  {
    char* hp = (char*)(Hst + ((size_t)(s + 1) * 2 + d) * 32768
                       + (size_t)(ebg * 4) * 512 + u0 + ej);
    asm volatile(
      "global_store_short %0, %1, off sc0 sc1\n\t"
      "global_store_short %0, %2, off offset:1024 sc0 sc1\n\t"
      "global_store_short %0, %3, off offset:2048 sc0 sc1\n\t"
      "global_store_short %0, %4, off offset:3072 sc0 sc1\n\t"
      "s_waitcnt vmcnt(0)"
      :: "v"(hp), "v"(hu[0]), "v"(hu[1]), "v"(hu[2]), "v"(hu[3])
      : "memory");
  }
  __syncthreads();   // drains all waves' stores (compiler emits vmcnt(0))
  if (tid == 0)
    __hip_atomic_store(flg + ((size_t)(s + 1) * 2 + d) * 32 + cg, 1,
                       __ATOMIC_RELAXED, __HIP_MEMORY_SCOPE_AGENT);

  // ---- out stores (HBM, off the dependency chain) ----
  {
    const bool last = (s == T_ - 1);
#pragma unroll
    for (int r = 0; r < 4; ++r) {
      const int b = ebg * 4 + r;
      out[((size_t)b * T_ + t) * 1024 + d * 512 + u0 + ej] = hvv[r];
      if (last) {
        out[33554432u + (size_t)b * 1024 + d * 512 + u0 + ej] = hvv[r];
        out[33619968u + (size_t)b * 1024 + d * 512 + u0 + ej] = cvv[r];
      }
    }
  }
}

// ---------------- R8 fallback: step-per-launch (verbatim, proven) ----------
__global__ __launch_bounds__(256, 1)
void lstm_step(const int s, const int* __restrict__ enc, const unsigned short* __restrict__ embq,
               const unsigned short* __restrict__ Uq, const unsigned short* __restrict__ Wq,
               const float* __restrict__ bfv, const float* __restrict__ bbv,
               unsigned short* __restrict__ Hbf, float* __restrict__ Hf32,
               float* __restrict__ Cst, float* __restrict__ out) {
  const int tid = threadIdx.x;
  const int lane = tid & 63;
  const int wave = tid >> 6;
  const int mh = wave & 1, nh = wave >> 1;
  const int l15 = lane & 15, l4 = lane >> 4;
  const int d = blockIdx.x >> 5;
  const int cg = blockIdx.x & 31;
  const int u0 = cg * 16;
  const int t = d ? (T_ - 1 - s) : s;

  __shared__ float Z[64][68];

  const unsigned short* ub = Uq + ((size_t)((d * 32 + cg) * 2 + nh)) * (16 * 2 * 512);
  const unsigned short* wb = Wq + ((size_t)((d * 32 + cg) * 2 + nh)) * (8 * 2 * 512);
  bf16x8 u_frag[16][2];
#pragma unroll
  for (int ks = 0; ks < 16; ++ks)
#pragma unroll
    for (int ns = 0; ns < 2; ++ns)
      u_frag[ks][ns] = *(const bf16x8*)(ub + (size_t)(ks * 2 + ns) * 512 + lane * 8);
  bf16x8 w_frag[8][2];
#pragma unroll
  for (int ks = 0; ks < 8; ++ks)
#pragma unroll
    for (int ns = 0; ns < 2; ++ns)
      w_frag[ks][ns] = *(const bf16x8*)(wb + (size_t)(ks * 2 + ns) * 512 + lane * 8);

  bf16x8 apf[8][2];
  {
    const unsigned short* eT = embq + (size_t)t * (B_ * E_);
#pragma unroll
    for (int ks = 0; ks < 8; ++ks)
#pragma unroll
      for (int ms = 0; ms < 2; ++ms) {
        const int b = mh * 32 + ms * 16 + l15;
        apf[ks][ms] = *(const bf16x8*)(eT + b * E_ + ks * 32 + l4 * 8);
      }
  }
  const int ej = tid & 15;
  const int ebg = tid >> 4;
  int mpf[4];
#pragma unroll
  for (int r = 0; r < 4; ++r) mpf[r] = enc[(ebg * 4 + r) * T_ + t];

  f32x4 acc[2][2];
#pragma unroll
  for (int ms = 0; ms < 2; ++ms)
#pragma unroll
    for (int ns = 0; ns < 2; ++ns) acc[ms][ns] = (f32x4)0.0f;

#pragma unroll
  for (int ks = 0; ks < 8; ++ks)
#pragma unroll
    for (int ms = 0; ms < 2; ++ms)
#pragma unroll
      for (int ns = 0; ns < 2; ++ns)
        acc[ms][ns] = __builtin_amdgcn_mfma_f32_16x16x32_bf16(apf[ks][ms], w_frag[ks][ns],
                                                              acc[ms][ns], 0, 0, 0);

  if (s > 0) {
    const unsigned short* Hrd = Hbf + ((size_t)((s & 1) * 2 + d)) * (B_ * 512);
    bf16x8 ha[16][2];
#pragma unroll
    for (int ks = 0; ks < 16; ++ks)
#pragma unroll
      for (int ms = 0; ms < 2; ++ms) {
        const int b = mh * 32 + ms * 16 + l15;
        ha[ks][ms] = *(const bf16x8*)(Hrd + (size_t)b * 512 + ks * 32 + l4 * 8);
      }
#pragma unroll
    for (int ks = 0; ks < 16; ++ks) {
      acc[0][0] = __builtin_amdgcn_mfma_f32_16x16x32_bf16(ha[ks][0], u_frag[ks][0], acc[0][0], 0, 0, 0);
      acc[0][1] = __builtin_amdgcn_mfma_f32_16x16x32_bf16(ha[ks][0], u_frag[ks][1], acc[0][1], 0, 0, 0);
      acc[1][0] = __builtin_amdgcn_mfma_f32_16x16x32_bf16(ha[ks][1], u_frag[ks][0], acc[1][0], 0, 0, 0);
      acc[1][1] = __builtin_amdgcn_mfma_f32_16x16x32_bf16(ha[ks][1], u_frag[ks][1], acc[1][1], 0, 0, 0);
    }
  }

#pragma unroll
  for (int ms = 0; ms < 2; ++ms)
#pragma unroll
    for (int ns = 0; ns < 2; ++ns)
#pragma unroll
      for (int r = 0; r < 4; ++r)
        Z[mh * 32 + ms * 16 + l4 * 4 + r][nh * 32 + ns * 16 + l15] = acc[ms][ns][r];
  __syncthreads();

  const float* bd = d ? bbv : bfv;
  float bias[4];
#pragma unroll
  for (int g = 0; g < 4; ++g) bias[g] = bd[g * 512 + u0 + ej];

  float* Hf = Hf32 + (size_t)d * (B_ * 512);
  float* Cf = Cst + (size_t)d * (B_ * 512);
  unsigned short* Hwr = Hbf + ((size_t)(((s + 1) & 1) * 2 + d)) * (B_ * 512);
  const bool last = (s == T_ - 1);
#pragma unroll
  for (int r = 0; r < 4; ++r) {
    const int b = ebg * 4 + r;
    const size_t si = (size_t)b * 512 + u0 + ej;
    float zi = Z[b][ej] + bias[0];
    float zf = Z[b][16 + ej] + bias[1];
    float zg = Z[b][32 + ej] + bias[2];
    float zo = Z[b][48 + ej] + bias[3];
    float ig = sigm(zi), fg = sigm(zf), gg = tanh_(zg), og = sigm(zo);
    float hp = Hf[si], cp = Cf[si];
    float cn = fg * cp + ig * gg;
    float hn = og * tanh_(cn);
    const bool m = (mpf[r] != 0);
    float hv = m ? hn : hp;
    float cv = m ? cn : cp;
    Hf[si] = hv;
    Cf[si] = cv;
    Hwr[si] = f2bf(hv);
    out[((size_t)b * T_ + t) * 1024 + d * 512 + u0 + ej] = hv;
    if (last) {
      out[33554432u + (size_t)b * 1024 + d * 512 + u0 + ej] = hv;
      out[33619968u + (size_t)b * 1024 + d * 512 + u0 + ej] = cv;
    }
  }
}

extern "C" void kernel_launch(void* const* d_in, const int* in_sizes, int n_in,
                              void* d_out, int out_size, void* d_ws, size_t ws_size,
                              hipStream_t stream) {
  const int* enc = (const int*)d_in[0];
  const float* emb = (const float*)d_in[1];
  const float* Wf = (const float*)d_in[2];
  const float* Uf = (const float*)d_in[3];
  const float* bf = (const float*)d_in[4];
  const float* Wb = (const float*)d_in[5];
  const float* Ub = (const float*)d_in[6];
  const float* bb = (const float*)d_in[7];
  float* out = (float*)d_out;
  char* ws = (char*)d_ws;

  // shared prep regions
  unsigned short* embq = (unsigned short*)ws;                  // 16 MiB
  unsigned short* Uq  = (unsigned short*)(ws + 16777216u);     // 4 MiB
  unsigned short* Wq  = (unsigned short*)(ws + 20971520u);     // 2 MiB

  // primary (DAG) layout: needs 90,964,224 B total
  const size_t OFF_HST = 23068672u;                            // [513][2][64][512] bf16, 65.7 MB
  const size_t OFF_HF  = 90308608u;                            // [2][64][512] f32
  const size_t OFF_CS  = 90570752u;                            // [2][64][512] f32
  const size_t OFF_FLG = 90832896u;                            // [513][2][32] int
  const size_t NEED    = 90964224u;

  prep_kernel<<<32768, 64, 0, stream>>>(enc, emb, embq);
  prep_w<<<6144, 64, 0, stream>>>(Wf, Uf, Wb, Ub, Uq, Wq);

  if (ws_size >= NEED) {
    unsigned short* Hst = (unsigned short*)(ws + OFF_HST);
    float* Hf32 = (float*)(ws + OFF_HF);
    float* Cst  = (float*)(ws + OFF_CS);
    int*   flg  = (int*)(ws + OFF_FLG);
    // zero state + flags (contiguous)
    hipMemsetAsync(ws + OFF_HF, 0, NEED - OFF_HF, stream);
    lstm_dag<<<32768, 256, 0, stream>>>(enc, embq, Uq, Wq, bf, bb,
                                        Hst, Hf32, Cst, flg, out);
  } else {
    // fallback: verbatim R8 step-per-launch (proven pass at 7037 us)
    unsigned short* Hbf = (unsigned short*)(ws + 23068672u);
    float* Hf32 = (float*)(ws + 23330816u);
    float* Cst  = (float*)(ws + 23592960u);
    hipMemsetAsync(ws + 23068672u, 0, 786432u, stream);
    for (int s = 0; s < 512; ++s)
      lstm_step<<<64, 256, 0, stream>>>(s, enc, embq, Uq, Wq, bf, bb, Hbf, Hf32, Cst, out);
  }
}

// Round 7
// 4555.276 us; speedup vs baseline: 1.5449x; 1.0003x over previous
//
#include <hip/hip_runtime.h>
#include <cstdint>

// Bidirectional masked LSTM encoder, B=64, T=512, E=256, U=512, G=2048.
// R10: DAG skeleton from R9 (PROVEN live: step-s blocks wait only on
// lower-blockIdx step-(s-1) blocks; FIFO dispatch => progress with even one
// free CU slot). R9 measured 8.6us/step with FETCH/WRITE +260MB each vs R0:
// the per-element __hip_atomic Hf32/Cst state round-trip hit HBM and its
// 8+8 per-thread atomic ops serialized on the critical path. R10 changes:
//  1) h/c f32 state -> parity ping-pong float2 buffer, accessed by batched
//     sc0 sc1 asm folded into the existing H-load / publish asm blocks
//     (ONE vmcnt drain each, R3-proven pattern; no per-op waits, LLC-hot).
//  2) Hst per-step (67MB, LLC-sweeping) -> parity-2 (256KB, LLC-resident).
//     Safe: level-(s+1) writers of slot parity(s) run only after all
//     flags[s+1], each set only after that block's reads of H(s) drained.
//  3) s_setprio(1) on the active section (poll-exit..publish-drain).
// Flags, poll loop (atomic_load+ballot+s_sleep), flag store: byte-identical
// to R9. Fallback to verbatim R8 step-per-launch if ws too small (can't
// trigger now: NEED=25.6MB).

#define B_ 64
#define T_ 512
#define E_ 256

typedef __attribute__((ext_vector_type(8))) short bf16x8;
typedef __attribute__((ext_vector_type(4))) float f32x4;
typedef __attribute__((ext_vector_type(2))) float f32x2;

__device__ __forceinline__ unsigned short f2bf(float x) {
  unsigned u = __float_as_uint(x);
  u += 0x7FFFu + ((u >> 16) & 1u);      // round-to-nearest-even
  return (unsigned short)(u >> 16);
}
__device__ __forceinline__ float sigm(float x) { return 1.0f / (1.0f + __expf(-x)); }
__device__ __forceinline__ float tanh_(float x) { return 1.0f - 2.0f / (__expf(2.0f * x) + 1.0f); }

// Gather + f32->bf16 cast of the embedded sequence into [t][b][e] layout.
__global__ void prep_kernel(const int* __restrict__ enc, const float* __restrict__ emb,
                            unsigned short* __restrict__ o) {
  const int bi = blockIdx.x;
  const int t = bi >> 6, b = bi & 63;
  const int tok = enc[b * T_ + t];
  float4 v = ((const float4*)(emb + (size_t)tok * E_))[threadIdx.x];
  ushort4 w;
  w.x = f2bf(v.x); w.y = f2bf(v.y); w.z = f2bf(v.z); w.w = f2bf(v.w);
  ((ushort4*)(o + (size_t)t * (B_ * E_) + b * E_))[threadIdx.x] = w;
}

// One-time weight repack: f32 [K][2048] -> fragment-ordered bf16 (per-thread
// contiguous bf16x8 MFMA B-frags). Layouts as R8/R9 (verified).
__global__ void prep_w(const float* __restrict__ Wf, const float* __restrict__ Uf,
                       const float* __restrict__ Wb, const float* __restrict__ Ub,
                       unsigned short* __restrict__ Uq, unsigned short* __restrict__ Wq) {
  int bi = blockIdx.x;
  const int ns = bi & 1; bi >>= 1;
  const int kk = bi % 24; bi /= 24;
  const int nh = bi & 1; bi >>= 1;
  const int cg = bi & 31; bi >>= 5;
  const int d = bi;
  const int lane = threadIdx.x;
  const int l15 = lane & 15, l4 = lane >> 4;
  const bool isU = (kk < 16);
  const float* src = isU ? (d ? Ub : Uf) : (d ? Wb : Wf);
  const int ks = isU ? kk : (kk - 16);
  const int col = (nh * 2 + ns) * 512 + cg * 16 + l15;
  const int row0 = ks * 32 + l4 * 8;
  bf16x8 f;
#pragma unroll
  for (int i = 0; i < 8; ++i) f[i] = (short)f2bf(src[(size_t)(row0 + i) * 2048 + col]);
  unsigned short* dst = isU
    ? Uq + ((size_t)(((d * 32 + cg) * 2 + nh) * 16 + ks) * 2 + ns) * 512 + lane * 8
    : Wq + ((size_t)(((d * 32 + cg) * 2 + nh) * 8 + ks) * 2 + ns) * 512 + lane * 8;
  *(bf16x8*)dst = f;
}

// ---------------- R10 primary: pipelined step-DAG, one grid ----------------
// grid 32768 = 512 steps x 64 (d,cg). Hst parity [2][2][64][512] bf16;
// SC parity [2][2][64][512] float2 (h,c).
__global__ __launch_bounds__(256, 1)
void lstm_dag(const int* __restrict__ enc, const unsigned short* __restrict__ embq,
              const unsigned short* __restrict__ Uq, const unsigned short* __restrict__ Wq,
              const float* __restrict__ bfv, const float* __restrict__ bbv,
              unsigned short* __restrict__ Hst, f32x2* __restrict__ SC,
              int* __restrict__ flg, float* __restrict__ out) {
  const int s = blockIdx.x >> 6;
  const int inner = blockIdx.x & 63;
  const int d = inner >> 5;
  const int cg = inner & 31;
  const int tid = threadIdx.x;
  const int lane = tid & 63;
  const int wave = tid >> 6;
  const int mh = wave & 1, nh = wave >> 1;
  const int l15 = lane & 15, l4 = lane >> 4;
  const int u0 = cg * 16;
  const int t = d ? (T_ - 1 - s) : s;

  __shared__ float Z[64][68];

  // ---- weight frags (coalesced 16B/lane, L2-hot after warmup) ----
  const unsigned short* ub = Uq + ((size_t)((d * 32 + cg) * 2 + nh)) * (16 * 2 * 512);
  const unsigned short* wb = Wq + ((size_t)((d * 32 + cg) * 2 + nh)) * (8 * 2 * 512);
  bf16x8 u_frag[16][2];
#pragma unroll
  for (int ks = 0; ks < 16; ++ks)
#pragma unroll
    for (int ns = 0; ns < 2; ++ns)
      u_frag[ks][ns] = *(const bf16x8*)(ub + (size_t)(ks * 2 + ns) * 512 + lane * 8);
  bf16x8 w_frag[8][2];
#pragma unroll
  for (int ks = 0; ks < 8; ++ks)
#pragma unroll
    for (int ns = 0; ns < 2; ++ns)
      w_frag[ks][ns] = *(const bf16x8*)(wb + (size_t)(ks * 2 + ns) * 512 + lane * 8);

  // ---- emb A-frags + mask ----
  bf16x8 apf[8][2];
  {
    const unsigned short* eT = embq + (size_t)t * (B_ * E_);
#pragma unroll
    for (int ks = 0; ks < 8; ++ks)
#pragma unroll
      for (int ms = 0; ms < 2; ++ms) {
        const int b = mh * 32 + ms * 16 + l15;
        apf[ks][ms] = *(const bf16x8*)(eT + b * E_ + ks * 32 + l4 * 8);
      }
  }
  const int ej = tid & 15;
  const int ebg = tid >> 4;
  int mpf[4];
#pragma unroll
  for (int r = 0; r < 4; ++r) mpf[r] = enc[(ebg * 4 + r) * T_ + t];

  f32x4 acc[2][2];
#pragma unroll
  for (int ms = 0; ms < 2; ++ms)
#pragma unroll
    for (int ns = 0; ns < 2; ++ns) acc[ms][ns] = (f32x4)0.0f;

  // ---- x-part: emb @ W (independent of predecessors: before the wait) ----
#pragma unroll
  for (int ks = 0; ks < 8; ++ks)
#pragma unroll
    for (int ms = 0; ms < 2; ++ms)
#pragma unroll
      for (int ns = 0; ns < 2; ++ns)
        acc[ms][ns] = __builtin_amdgcn_mfma_f32_16x16x32_bf16(apf[ks][ms], w_frag[ks][ns],
                                                              acc[ms][ns], 0, 0, 0);

  f32x2 hc_in[4];
#pragma unroll
  for (int r = 0; r < 4; ++r) hc_in[r] = (f32x2)0.0f;

  if (s > 0) {
    // ---- wait: all 32 (d,cg') blocks of step s-1 have published ----
    // (byte-identical poll to R9: atomic_load + ballot + s_sleep)
    int* fp = flg + ((size_t)s * 2 + d) * 32;
    {
      int v; bool first = true;
      do {
        if (!first) __builtin_amdgcn_s_sleep(2);
        first = false;
        v = __hip_atomic_load(fp + (lane & 31), __ATOMIC_RELAXED, __HIP_MEMORY_SCOPE_AGENT);
      } while (__ballot(v == 0) != 0ull);
    }
    __builtin_amdgcn_s_setprio(1);

    // ---- h-part A-frags + own (h,c) state: ONE asm block, 36 sc0 sc1
    //      loads, single vmcnt(0). Hst[par] layout [d][b][512u]. ----
    bf16x8 ha[16][2];
    {
      const char* hb0 = (const char*)(Hst + ((size_t)(s & 1) * 2 + d) * 32768)
                        + (mh * 32 + l15) * 1024 + l4 * 16;
      const char* hb1 = hb0 + 16384;   // ms=1: +16 batches
      const char* sp0 = (const char*)(SC + ((size_t)(s & 1) * 2 + d) * 32768
                                      + (size_t)(ebg * 4) * 512 + u0 + ej);
      const char* sp1 = sp0 + 4096;
      const char* sp2 = sp0 + 8192;
      const char* sp3 = sp0 + 12288;
      asm volatile(
        "global_load_dwordx4 %0, %36, off offset:0 sc0 sc1\n\t"
        "global_load_dwordx4 %1, %36, off offset:64 sc0 sc1\n\t"
        "global_load_dwordx4 %2, %36, off offset:128 sc0 sc1\n\t"
        "global_load_dwordx4 %3, %36, off offset:192 sc0 sc1\n\t"
        "global_load_dwordx4 %4, %36, off offset:256 sc0 sc1\n\t"
        "global_load_dwordx4 %5, %36, off offset:320 sc0 sc1\n\t"
        "global_load_dwordx4 %6, %36, off offset:384 sc0 sc1\n\t"
        "global_load_dwordx4 %7, %36, off offset:448 sc0 sc1\n\t"
        "global_load_dwordx4 %8, %36, off offset:512 sc0 sc1\n\t"
        "global_load_dwordx4 %9, %36, off offset:576 sc0 sc1\n\t"
        "global_load_dwordx4 %10, %36, off offset:640 sc0 sc1\n\t"
        "global_load_dwordx4 %11, %36, off offset:704 sc0 sc1\n\t"
        "global_load_dwordx4 %12, %36, off offset:768 sc0 sc1\n\t"
        "global_load_dwordx4 %13, %36, off offset:832 sc0 sc1\n\t"
        "global_load_dwordx4 %14, %36, off offset:896 sc0 sc1\n\t"
        "global_load_dwordx4 %15, %36, off offset:960 sc0 sc1\n\t"
        "global_load_dwordx4 %16, %37, off offset:0 sc0 sc1\n\t"
        "global_load_dwordx4 %17, %37, off offset:64 sc0 sc1\n\t"
        "global_load_dwordx4 %18, %37, off offset:128 sc0 sc1\n\t"
        "global_load_dwordx4 %19, %37, off offset:192 sc0 sc1\n\t"
        "global_load_dwordx4 %20, %37, off offset:256 sc0 sc1\n\t"
        "global_load_dwordx4 %21, %37, off offset:320 sc0 sc1\n\t"
        "global_load_dwordx4 %22, %37, off offset:384 sc0 sc1\n\t"
        "global_load_dwordx4 %23, %37, off offset:448 sc0 sc1\n\t"
        "global_load_dwordx4 %24, %37, off offset:512 sc0 sc1\n\t"
        "global_load_dwordx4 %25, %37, off offset:576 sc0 sc1\n\t"
        "global_load_dwordx4 %26, %37, off offset:640 sc0 sc1\n\t"
        "global_load_dwordx4 %27, %37, off offset:704 sc0 sc1\n\t"
        "global_load_dwordx4 %28, %37, off offset:768 sc0 sc1\n\t"
        "global_load_dwordx4 %29, %37, off offset:832 sc0 sc1\n\t"
        "global_load_dwordx4 %30, %37, off offset:896 sc0 sc1\n\t"
        "global_load_dwordx4 %31, %37, off offset:960 sc0 sc1\n\t"
        "global_load_dwordx2 %32, %38, off sc0 sc1\n\t"
        "global_load_dwordx2 %33, %39, off sc0 sc1\n\t"
        "global_load_dwordx2 %34, %40, off sc0 sc1\n\t"
        "global_load_dwordx2 %35, %41, off sc0 sc1\n\t"
        "s_waitcnt vmcnt(0)"
        : "=v"(ha[0][0]), "=v"(ha[1][0]), "=v"(ha[2][0]), "=v"(ha[3][0]),
          "=v"(ha[4][0]), "=v"(ha[5][0]), "=v"(ha[6][0]), "=v"(ha[7][0]),
          "=v"(ha[8][0]), "=v"(ha[9][0]), "=v"(ha[10][0]), "=v"(ha[11][0]),
          "=v"(ha[12][0]), "=v"(ha[13][0]), "=v"(ha[14][0]), "=v"(ha[15][0]),
          "=v"(ha[0][1]), "=v"(ha[1][1]), "=v"(ha[2][1]), "=v"(ha[3][1]),
          "=v"(ha[4][1]), "=v"(ha[5][1]), "=v"(ha[6][1]), "=v"(ha[7][1]),
          "=v"(ha[8][1]), "=v"(ha[9][1]), "=v"(ha[10][1]), "=v"(ha[11][1]),
          "=v"(ha[12][1]), "=v"(ha[13][1]), "=v"(ha[14][1]), "=v"(ha[15][1]),
          "=v"(hc_in[0]), "=v"(hc_in[1]), "=v"(hc_in[2]), "=v"(hc_in[3])
        : "v"(hb0), "v"(hb1), "v"(sp0), "v"(sp1), "v"(sp2), "v"(sp3)
        : "memory");
    }
#pragma unroll
    for (int ks = 0; ks < 16; ++ks) {
      acc[0][0] = __builtin_amdgcn_mfma_f32_16x16x32_bf16(ha[ks][0], u_frag[ks][0], acc[0][0], 0, 0, 0);
      acc[0][1] = __builtin_amdgcn_mfma_f32_16x16x32_bf16(ha[ks][0], u_frag[ks][1], acc[0][1], 0, 0, 0);
      acc[1][0] = __builtin_amdgcn_mfma_f32_16x16x32_bf16(ha[ks][1], u_frag[ks][0], acc[1][0], 0, 0, 0);
      acc[1][1] = __builtin_amdgcn_mfma_f32_16x16x32_bf16(ha[ks][1], u_frag[ks][1], acc[1][1], 0, 0, 0);
    }
  }

  // ---- regroup gates per (b,u) via LDS ----
#pragma unroll
  for (int ms = 0; ms < 2; ++ms)
#pragma unroll
    for (int ns = 0; ns < 2; ++ns)
#pragma unroll
      for (int r = 0; r < 4; ++r)
        Z[mh * 32 + ms * 16 + l4 * 4 + r][nh * 32 + ns * 16 + l15] = acc[ms][ns][r];
  __syncthreads();

  // ---- cell + masked carry (all register-resident) ----
  const float* bd = d ? bbv : bfv;
  float bias[4];
#pragma unroll
  for (int g = 0; g < 4; ++g) bias[g] = bd[g * 512 + u0 + ej];

  f32x2 hc[4];
  unsigned hu[4];
#pragma unroll
  for (int r = 0; r < 4; ++r) {
    const int b = ebg * 4 + r;
    float zi = Z[b][ej] + bias[0];
    float zf = Z[b][16 + ej] + bias[1];
    float zg = Z[b][32 + ej] + bias[2];
    float zo = Z[b][48 + ej] + bias[3];
    float ig = sigm(zi), fg = sigm(zf), gg = tanh_(zg), og = sigm(zo);
    float cn = fg * hc_in[r][1] + ig * gg;
    float hn = og * tanh_(cn);
    const bool m = (mpf[r] != 0);
    hc[r][0] = m ? hn : hc_in[r][0];
    hc[r][1] = m ? cn : hc_in[r][1];
    hu[r] = (unsigned)f2bf(hc[r][0]);
  }

  // ---- publish H(s+1) bf16 + (h,c) f32 state: ONE asm block, 8 sc0 sc1
  //      stores, single drain ----
  {
    char* hp = (char*)(Hst + ((size_t)((s + 1) & 1) * 2 + d) * 32768
                       + (size_t)(ebg * 4) * 512 + u0 + ej);
    char* wp0 = (char*)(SC + ((size_t)((s + 1) & 1) * 2 + d) * 32768
                        + (size_t)(ebg * 4) * 512 + u0 + ej);
    char* wp1 = wp0 + 4096;
    char* wp2 = wp0 + 8192;
    char* wp3 = wp0 + 12288;
    asm volatile(
      "global_store_short %0, %1, off sc0 sc1\n\t"
      "global_store_short %0, %2, off offset:1024 sc0 sc1\n\t"
      "global_store_short %0, %3, off offset:2048 sc0 sc1\n\t"
      "global_store_short %0, %4, off offset:3072 sc0 sc1\n\t"
      "global_store_dwordx2 %5, %9, off sc0 sc1\n\t"
      "global_store_dwordx2 %6, %10, off sc0 sc1\n\t"
      "global_store_dwordx2 %7, %11, off sc0 sc1\n\t"
      "global_store_dwordx2 %8, %12, off sc0 sc1\n\t"
      "s_waitcnt vmcnt(0)"
      :: "v"(hp), "v"(hu[0]), "v"(hu[1]), "v"(hu[2]), "v"(hu[3]),
         "v"(wp0), "v"(wp1), "v"(wp2), "v"(wp3),
         "v"(hc[0]), "v"(hc[1]), "v"(hc[2]), "v"(hc[3])
      : "memory");
  }
  __syncthreads();   // all waves' publishes drained before the flag
  if (tid == 0)
    __hip_atomic_store(flg + ((size_t)(s + 1) * 2 + d) * 32 + cg, 1,
                       __ATOMIC_RELAXED, __HIP_MEMORY_SCOPE_AGENT);
  __builtin_amdgcn_s_setprio(0);

  // ---- out stores (HBM, off the dependency chain) ----
  {
    const bool last = (s == T_ - 1);
#pragma unroll
    for (int r = 0; r < 4; ++r) {
      const int b = ebg * 4 + r;
      out[((size_t)b * T_ + t) * 1024 + d * 512 + u0 + ej] = hc[r][0];
      if (last) {
        out[33554432u + (size_t)b * 1024 + d * 512 + u0 + ej] = hc[r][0];
        out[33619968u + (size_t)b * 1024 + d * 512 + u0 + ej] = hc[r][1];
      }
    }
  }
}

// ---------------- R8 fallback: step-per-launch (verbatim, proven) ----------
__global__ __launch_bounds__(256, 1)
void lstm_step(const int s, const int* __restrict__ enc, const unsigned short* __restrict__ embq,
               const unsigned short* __restrict__ Uq, const unsigned short* __restrict__ Wq,
               const float* __restrict__ bfv, const float* __restrict__ bbv,
               unsigned short* __restrict__ Hbf, float* __restrict__ Hf32,
               float* __restrict__ Cst, float* __restrict__ out) {
  const int tid = threadIdx.x;
  const int lane = tid & 63;
  const int wave = tid >> 6;
  const int mh = wave & 1, nh = wave >> 1;
  const int l15 = lane & 15, l4 = lane >> 4;
  const int d = blockIdx.x >> 5;
  const int cg = blockIdx.x & 31;
  const int u0 = cg * 16;
  const int t = d ? (T_ - 1 - s) : s;

  __shared__ float Z[64][68];

  const unsigned short* ub = Uq + ((size_t)((d * 32 + cg) * 2 + nh)) * (16 * 2 * 512);
  const unsigned short* wb = Wq + ((size_t)((d * 32 + cg) * 2 + nh)) * (8 * 2 * 512);
  bf16x8 u_frag[16][2];
#pragma unroll
  for (int ks = 0; ks < 16; ++ks)
#pragma unroll
    for (int ns = 0; ns < 2; ++ns)
      u_frag[ks][ns] = *(const bf16x8*)(ub + (size_t)(ks * 2 + ns) * 512 + lane * 8);
  bf16x8 w_frag[8][2];
#pragma unroll
  for (int ks = 0; ks < 8; ++ks)
#pragma unroll
    for (int ns = 0; ns < 2; ++ns)
      w_frag[ks][ns] = *(const bf16x8*)(wb + (size_t)(ks * 2 + ns) * 512 + lane * 8);

  bf16x8 apf[8][2];
  {
    const unsigned short* eT = embq + (size_t)t * (B_ * E_);
#pragma unroll
    for (int ks = 0; ks < 8; ++ks)
#pragma unroll
      for (int ms = 0; ms < 2; ++ms) {
        const int b = mh * 32 + ms * 16 + l15;
        apf[ks][ms] = *(const bf16x8*)(eT + b * E_ + ks * 32 + l4 * 8);
      }
  }
  const int ej = tid & 15;
  const int ebg = tid >> 4;
  int mpf[4];
#pragma unroll
  for (int r = 0; r < 4; ++r) mpf[r] = enc[(ebg * 4 + r) * T_ + t];

  f32x4 acc[2][2];
#pragma unroll
  for (int ms = 0; ms < 2; ++ms)
#pragma unroll
    for (int ns = 0; ns < 2; ++ns) acc[ms][ns] = (f32x4)0.0f;

#pragma unroll
  for (int ks = 0; ks < 8; ++ks)
#pragma unroll
    for (int ms = 0; ms < 2; ++ms)
#pragma unroll
      for (int ns = 0; ns < 2; ++ns)
        acc[ms][ns] = __builtin_amdgcn_mfma_f32_16x16x32_bf16(apf[ks][ms], w_frag[ks][ns],
                                                              acc[ms][ns], 0, 0, 0);

  if (s > 0) {
    const unsigned short* Hrd = Hbf + ((size_t)((s & 1) * 2 + d)) * (B_ * 512);
    bf16x8 ha[16][2];
#pragma unroll
    for (int ks = 0; ks < 16; ++ks)
#pragma unroll
      for (int ms = 0; ms < 2; ++ms) {
        const int b = mh * 32 + ms * 16 + l15;
        ha[ks][ms] = *(const bf16x8*)(Hrd + (size_t)b * 512 + ks * 32 + l4 * 8);
      }
#pragma unroll
    for (int ks = 0; ks < 16; ++ks) {
      acc[0][0] = __builtin_amdgcn_mfma_f32_16x16x32_bf16(ha[ks][0], u_frag[ks][0], acc[0][0], 0, 0, 0);
      acc[0][1] = __builtin_amdgcn_mfma_f32_16x16x32_bf16(ha[ks][0], u_frag[ks][1], acc[0][1], 0, 0, 0);
      acc[1][0] = __builtin_amdgcn_mfma_f32_16x16x32_bf16(ha[ks][1], u_frag[ks][0], acc[1][0], 0, 0, 0);
      acc[1][1] = __builtin_amdgcn_mfma_f32_16x16x32_bf16(ha[ks][1], u_frag[ks][1], acc[1][1], 0, 0, 0);
    }
  }

#pragma unroll
  for (int ms = 0; ms < 2; ++ms)
#pragma unroll
    for (int ns = 0; ns < 2; ++ns)
#pragma unroll
      for (int r = 0; r < 4; ++r)
        Z[mh * 32 + ms * 16 + l4 * 4 + r][nh * 32 + ns * 16 + l15] = acc[ms][ns][r];
  __syncthreads();

  const float* bd = d ? bbv : bfv;
  float bias[4];
#pragma unroll
  for (int g = 0; g < 4; ++g) bias[g] = bd[g * 512 + u0 + ej];

  float* Hf = Hf32 + (size_t)d * (B_ * 512);
  float* Cf = Cst + (size_t)d * (B_ * 512);
  unsigned short* Hwr = Hbf + ((size_t)(((s + 1) & 1) * 2 + d)) * (B_ * 512);
  const bool last = (s == T_ - 1);
#pragma unroll
  for (int r = 0; r < 4; ++r) {
    const int b = ebg * 4 + r;
    const size_t si = (size_t)b * 512 + u0 + ej;
    float zi = Z[b][ej] + bias[0];
    float zf = Z[b][16 + ej] + bias[1];
    float zg = Z[b][32 + ej] + bias[2];
    float zo = Z[b][48 + ej] + bias[3];
    float ig = sigm(zi), fg = sigm(zf), gg = tanh_(zg), og = sigm(zo);
    float hp = Hf[si], cp = Cf[si];
    float cn = fg * cp + ig * gg;
    float hn = og * tanh_(cn);
    const bool m = (mpf[r] != 0);
    float hv = m ? hn : hp;
    float cv = m ? cn : cp;
    Hf[si] = hv;
    Cf[si] = cv;
    Hwr[si] = f2bf(hv);
    out[((size_t)b * T_ + t) * 1024 + d * 512 + u0 + ej] = hv;
    if (last) {
      out[33554432u + (size_t)b * 1024 + d * 512 + u0 + ej] = hv;
      out[33619968u + (size_t)b * 1024 + d * 512 + u0 + ej] = cv;
    }
  }
}

extern "C" void kernel_launch(void* const* d_in, const int* in_sizes, int n_in,
                              void* d_out, int out_size, void* d_ws, size_t ws_size,
                              hipStream_t stream) {
  const int* enc = (const int*)d_in[0];
  const float* emb = (const float*)d_in[1];
  const float* Wf = (const float*)d_in[2];
  const float* Uf = (const float*)d_in[3];
  const float* bf = (const float*)d_in[4];
  const float* Wb = (const float*)d_in[5];
  const float* Ub = (const float*)d_in[6];
  const float* bb = (const float*)d_in[7];
  float* out = (float*)d_out;
  char* ws = (char*)d_ws;

  // shared prep regions
  unsigned short* embq = (unsigned short*)ws;                  // 16 MiB
  unsigned short* Uq  = (unsigned short*)(ws + 16777216u);     // 4 MiB
  unsigned short* Wq  = (unsigned short*)(ws + 20971520u);     // 2 MiB

  // primary (DAG) layout: 25.6 MB total
  const size_t OFF_HST = 23068672u;                            // [2][2][64][512] bf16, 256 KiB
  const size_t OFF_SC  = 23330816u;                            // [2][2][64][512] float2, 2 MiB
  const size_t OFF_FLG = 25427968u;                            // [513][2][32] int, 128.25 KiB
  const size_t NEED    = 25559296u;

  prep_kernel<<<32768, 64, 0, stream>>>(enc, emb, embq);
  prep_w<<<6144, 64, 0, stream>>>(Wf, Uf, Wb, Ub, Uq, Wq);

  if (ws_size >= NEED) {
    unsigned short* Hst = (unsigned short*)(ws + OFF_HST);
    f32x2* SC = (f32x2*)(ws + OFF_SC);
    int*   flg = (int*)(ws + OFF_FLG);
    // zero state + flags (contiguous; Hst needs no zeroing: s=0 skips read)
    hipMemsetAsync(ws + OFF_SC, 0, NEED - OFF_SC, stream);
    lstm_dag<<<32768, 256, 0, stream>>>(enc, embq, Uq, Wq, bf, bb,
                                        Hst, SC, flg, out);
  } else {
    // fallback: verbatim R8 step-per-launch (proven pass at 7037 us)
    unsigned short* Hbf = (unsigned short*)(ws + 23068672u);
    float* Hf32 = (float*)(ws + 23330816u);
    float* Cst  = (float*)(ws + 23592960u);
    hipMemsetAsync(ws + 23068672u, 0, 786432u, stream);
    for (int s = 0; s < 512; ++s)
      lstm_step<<<64, 256, 0, stream>>>(s, enc, embq, Uq, Wq, bf, bb, Hbf, Hf32, Cst, out);
  }
}

// Round 9
// 3154.577 us; speedup vs baseline: 2.2308x; 1.4440x over previous
//
#include <hip/hip_runtime.h>
#include <cstdint>

// Bidirectional masked LSTM encoder, B=64, T=512, E=256, U=512, G=2048.
// R12 = R11 resubmitted byte-for-byte (previous round died to
// "MI355X container failed twice" -- infra, no kernel verdict; audit
// found no defect). DAG skeleton from R9/R10 (PROVEN live twice).
// R10 falsified traffic- and atomic-serialization theories (removed both,
// dur unchanged at 8.65us/level). Remaining theory: LLC CONGESTION -- (a)
// all 4 waves of every resident not-ready block spin-load flag lines; (b)
// publish = 65K separate 2B uncached store transactions per level (store_
// short x4/thread, [d][b][u] layout interleaves blocks on lines); (c) state
// reload 4 more small loads/thread. R11/R12 decongests, same bytes:
//  1) wave0-only poll + __syncthreads release, s_sleep(4) backoff.
//  2) Hst -> [d][cg][b][16u] (R0-proven frag addressing on the read side);
//     epilogue remap thread->(batch eb=tid>>2, unit-quad uq=tid&3): h-publish
//     is ONE coalesced dwordx2/thread (4x fewer, 4x larger transactions).
//  3) SC (h,c f32 pairs) -> block-owned contiguous chunk; reload/publish as
//     2x dwordx4/thread folded into the single-drain asm blocks. out stores
//     become dwordx4.
// Flags array, flag store, parity ping-pong, memset, grid: identical to R10.

#define B_ 64
#define T_ 512
#define E_ 256

typedef __attribute__((ext_vector_type(8))) short bf16x8;
typedef __attribute__((ext_vector_type(4))) float f32x4;
typedef __attribute__((ext_vector_type(2))) float f32x2;
typedef __attribute__((ext_vector_type(2))) unsigned u32x2;

__device__ __forceinline__ unsigned short f2bf(float x) {
  unsigned u = __float_as_uint(x);
  u += 0x7FFFu + ((u >> 16) & 1u);      // round-to-nearest-even
  return (unsigned short)(u >> 16);
}
__device__ __forceinline__ float sigm(float x) { return 1.0f / (1.0f + __expf(-x)); }
__device__ __forceinline__ float tanh_(float x) { return 1.0f - 2.0f / (__expf(2.0f * x) + 1.0f); }

// Gather + f32->bf16 cast of the embedded sequence into [t][b][e] layout.
__global__ void prep_kernel(const int* __restrict__ enc, const float* __restrict__ emb,
                            unsigned short* __restrict__ o) {
  const int bi = blockIdx.x;
  const int t = bi >> 6, b = bi & 63;
  const int tok = enc[b * T_ + t];
  float4 v = ((const float4*)(emb + (size_t)tok * E_))[threadIdx.x];
  ushort4 w;
  w.x = f2bf(v.x); w.y = f2bf(v.y); w.z = f2bf(v.z); w.w = f2bf(v.w);
  ((ushort4*)(o + (size_t)t * (B_ * E_) + b * E_))[threadIdx.x] = w;
}

// One-time weight repack: f32 [K][2048] -> fragment-ordered bf16 (per-thread
// contiguous bf16x8 MFMA B-frags). Layouts as R8/R9/R10 (verified).
__global__ void prep_w(const float* __restrict__ Wf, const float* __restrict__ Uf,
                       const float* __restrict__ Wb, const float* __restrict__ Ub,
                       unsigned short* __restrict__ Uq, unsigned short* __restrict__ Wq) {
  int bi = blockIdx.x;
  const int ns = bi & 1; bi >>= 1;
  const int kk = bi % 24; bi /= 24;
  const int nh = bi & 1; bi >>= 1;
  const int cg = bi & 31; bi >>= 5;
  const int d = bi;
  const int lane = threadIdx.x;
  const int l15 = lane & 15, l4 = lane >> 4;
  const bool isU = (kk < 16);
  const float* src = isU ? (d ? Ub : Uf) : (d ? Wb : Wf);
  const int ks = isU ? kk : (kk - 16);
  const int col = (nh * 2 + ns) * 512 + cg * 16 + l15;
  const int row0 = ks * 32 + l4 * 8;
  bf16x8 f;
#pragma unroll
  for (int i = 0; i < 8; ++i) f[i] = (short)f2bf(src[(size_t)(row0 + i) * 2048 + col]);
  unsigned short* dst = isU
    ? Uq + ((size_t)(((d * 32 + cg) * 2 + nh) * 16 + ks) * 2 + ns) * 512 + lane * 8
    : Wq + ((size_t)(((d * 32 + cg) * 2 + nh) * 8 + ks) * 2 + ns) * 512 + lane * 8;
  *(bf16x8*)dst = f;
}

// ---------------- R12 primary: pipelined step-DAG, one grid ----------------
// grid 32768 = 512 steps x 64 (d,cg). Hst parity [2][2][32cg][64b][16u] bf16;
// SC parity [2][2][32cg][64b][16u] float2 (h,c).
__global__ __launch_bounds__(256, 1)
void lstm_dag(const int* __restrict__ enc, const unsigned short* __restrict__ embq,
              const unsigned short* __restrict__ Uq, const unsigned short* __restrict__ Wq,
              const float* __restrict__ bfv, const float* __restrict__ bbv,
              unsigned short* __restrict__ Hst, f32x2* __restrict__ SC,
              int* __restrict__ flg, float* __restrict__ out) {
  const int s = blockIdx.x >> 6;
  const int inner = blockIdx.x & 63;
  const int d = inner >> 5;
  const int cg = inner & 31;
  const int tid = threadIdx.x;
  const int lane = tid & 63;
  const int wave = tid >> 6;
  const int mh = wave & 1, nh = wave >> 1;
  const int l15 = lane & 15, l4 = lane >> 4;
  const int u0 = cg * 16;
  const int t = d ? (T_ - 1 - s) : s;

  __shared__ float Z[64][68];

  // ---- weight frags (coalesced 16B/lane, L2-hot after warmup) ----
  const unsigned short* ub = Uq + ((size_t)((d * 32 + cg) * 2 + nh)) * (16 * 2 * 512);
  const unsigned short* wb = Wq + ((size_t)((d * 32 + cg) * 2 + nh)) * (8 * 2 * 512);
  bf16x8 u_frag[16][2];
#pragma unroll
  for (int ks = 0; ks < 16; ++ks)
#pragma unroll
    for (int ns = 0; ns < 2; ++ns)
      u_frag[ks][ns] = *(const bf16x8*)(ub + (size_t)(ks * 2 + ns) * 512 + lane * 8);
  bf16x8 w_frag[8][2];
#pragma unroll
  for (int ks = 0; ks < 8; ++ks)
#pragma unroll
    for (int ns = 0; ns < 2; ++ns)
      w_frag[ks][ns] = *(const bf16x8*)(wb + (size_t)(ks * 2 + ns) * 512 + lane * 8);

  // ---- emb A-frags + epilogue data ----
  bf16x8 apf[8][2];
  {
    const unsigned short* eT = embq + (size_t)t * (B_ * E_);
#pragma unroll
    for (int ks = 0; ks < 8; ++ks)
#pragma unroll
      for (int ms = 0; ms < 2; ++ms) {
        const int b = mh * 32 + ms * 16 + l15;
        apf[ks][ms] = *(const bf16x8*)(eT + b * E_ + ks * 32 + l4 * 8);
      }
  }
  // epilogue thread map: eb = batch (0..63), uq = unit-quad (0..3)
  const int eb = tid >> 2;
  const int uq = tid & 3;
  const int msk = enc[eb * T_ + t];
  const float* bd = d ? bbv : bfv;
  f32x4 bias[4];
#pragma unroll
  for (int g = 0; g < 4; ++g)
    bias[g] = *(const f32x4*)(bd + g * 512 + u0 + uq * 4);

  f32x4 acc[2][2];
#pragma unroll
  for (int ms = 0; ms < 2; ++ms)
#pragma unroll
    for (int ns = 0; ns < 2; ++ns) acc[ms][ns] = (f32x4)0.0f;

  // ---- x-part: emb @ W (independent of predecessors: before the wait) ----
#pragma unroll
  for (int ks = 0; ks < 8; ++ks)
#pragma unroll
    for (int ms = 0; ms < 2; ++ms)
#pragma unroll
      for (int ns = 0; ns < 2; ++ns)
        acc[ms][ns] = __builtin_amdgcn_mfma_f32_16x16x32_bf16(apf[ks][ms], w_frag[ks][ns],
                                                              acc[ms][ns], 0, 0, 0);

  f32x4 hin0 = (f32x4)0.0f, hin1 = (f32x4)0.0f;  // (h0,c0,h1,c1),(h2,c2,h3,c3)

  if (s > 0) {
    // ---- wait: wave0 polls the 32 level-(s-1) flags; others park at the
    //      barrier (75% less uncached poll traffic). ----
    if (wave == 0) {
      int* fp = flg + ((size_t)s * 2 + d) * 32;
      for (;;) {
        int v = __hip_atomic_load(fp + (lane & 31), __ATOMIC_RELAXED, __HIP_MEMORY_SCOPE_AGENT);
        if (__ballot(v == 0) == 0ull) break;
        __builtin_amdgcn_s_sleep(4);
      }
    }
    __syncthreads();
    __builtin_amdgcn_s_setprio(1);

    // ---- H(s) A-frags + own (h,c) state: ONE asm block, 34 sc0 sc1 loads,
    //      single vmcnt(0). Hst layout [cg][b][16u] (R0-proven addressing):
    //      frag byte off = ks*4096 + ms*512 + (l4>>1)*2048 + mh*1024 +
    //      l15*32 + (l4&1)*16 ----
    bf16x8 ha[16][2];
    {
      const char* Hrd = (const char*)(Hst + ((size_t)(s & 1) * 2 + d) * 32768);
      const char* lb = Hrd + (l4 >> 1) * 2048 + mh * 1024 + l15 * 32 + (l4 & 1) * 16;
      const char* b0p = lb + 0 * 8192 + 4096;
      const char* b1p = lb + 1 * 8192 + 4096;
      const char* b2p = lb + 2 * 8192 + 4096;
      const char* b3p = lb + 3 * 8192 + 4096;
      const char* b4p = lb + 4 * 8192 + 4096;
      const char* b5p = lb + 5 * 8192 + 4096;
      const char* b6p = lb + 6 * 8192 + 4096;
      const char* b7p = lb + 7 * 8192 + 4096;
      const char* sp0 = (const char*)(SC + ((size_t)(s & 1) * 2 + d) * 32768
                                      + (size_t)cg * 1024 + eb * 16 + uq * 4);
      asm volatile(
        "global_load_dwordx4 %0, %34, off offset:-4096 sc0 sc1\n\t"
        "global_load_dwordx4 %1, %34, off offset:-3584 sc0 sc1\n\t"
        "global_load_dwordx4 %2, %34, off offset:0 sc0 sc1\n\t"
        "global_load_dwordx4 %3, %34, off offset:512 sc0 sc1\n\t"
        "global_load_dwordx4 %4, %35, off offset:-4096 sc0 sc1\n\t"
        "global_load_dwordx4 %5, %35, off offset:-3584 sc0 sc1\n\t"
        "global_load_dwordx4 %6, %35, off offset:0 sc0 sc1\n\t"
        "global_load_dwordx4 %7, %35, off offset:512 sc0 sc1\n\t"
        "global_load_dwordx4 %8, %36, off offset:-4096 sc0 sc1\n\t"
        "global_load_dwordx4 %9, %36, off offset:-3584 sc0 sc1\n\t"
        "global_load_dwordx4 %10, %36, off offset:0 sc0 sc1\n\t"
        "global_load_dwordx4 %11, %36, off offset:512 sc0 sc1\n\t"
        "global_load_dwordx4 %12, %37, off offset:-4096 sc0 sc1\n\t"
        "global_load_dwordx4 %13, %37, off offset:-3584 sc0 sc1\n\t"
        "global_load_dwordx4 %14, %37, off offset:0 sc0 sc1\n\t"
        "global_load_dwordx4 %15, %37, off offset:512 sc0 sc1\n\t"
        "global_load_dwordx4 %16, %38, off offset:-4096 sc0 sc1\n\t"
        "global_load_dwordx4 %17, %38, off offset:-3584 sc0 sc1\n\t"
        "global_load_dwordx4 %18, %38, off offset:0 sc0 sc1\n\t"
        "global_load_dwordx4 %19, %38, off offset:512 sc0 sc1\n\t"
        "global_load_dwordx4 %20, %39, off offset:-4096 sc0 sc1\n\t"
        "global_load_dwordx4 %21, %39, off offset:-3584 sc0 sc1\n\t"
        "global_load_dwordx4 %22, %39, off offset:0 sc0 sc1\n\t"
        "global_load_dwordx4 %23, %39, off offset:512 sc0 sc1\n\t"
        "global_load_dwordx4 %24, %40, off offset:-4096 sc0 sc1\n\t"
        "global_load_dwordx4 %25, %40, off offset:-3584 sc0 sc1\n\t"
        "global_load_dwordx4 %26, %40, off offset:0 sc0 sc1\n\t"
        "global_load_dwordx4 %27, %40, off offset:512 sc0 sc1\n\t"
        "global_load_dwordx4 %28, %41, off offset:-4096 sc0 sc1\n\t"
        "global_load_dwordx4 %29, %41, off offset:-3584 sc0 sc1\n\t"
        "global_load_dwordx4 %30, %41, off offset:0 sc0 sc1\n\t"
        "global_load_dwordx4 %31, %41, off offset:512 sc0 sc1\n\t"
        "global_load_dwordx4 %32, %42, off sc0 sc1\n\t"
        "global_load_dwordx4 %33, %42, off offset:16 sc0 sc1\n\t"
        "s_waitcnt vmcnt(0)"
        : "=v"(ha[0][0]), "=v"(ha[0][1]), "=v"(ha[1][0]), "=v"(ha[1][1]),
          "=v"(ha[2][0]), "=v"(ha[2][1]), "=v"(ha[3][0]), "=v"(ha[3][1]),
          "=v"(ha[4][0]), "=v"(ha[4][1]), "=v"(ha[5][0]), "=v"(ha[5][1]),
          "=v"(ha[6][0]), "=v"(ha[6][1]), "=v"(ha[7][0]), "=v"(ha[7][1]),
          "=v"(ha[8][0]), "=v"(ha[8][1]), "=v"(ha[9][0]), "=v"(ha[9][1]),
          "=v"(ha[10][0]), "=v"(ha[10][1]), "=v"(ha[11][0]), "=v"(ha[11][1]),
          "=v"(ha[12][0]), "=v"(ha[12][1]), "=v"(ha[13][0]), "=v"(ha[13][1]),
          "=v"(ha[14][0]), "=v"(ha[14][1]), "=v"(ha[15][0]), "=v"(ha[15][1]),
          "=v"(hin0), "=v"(hin1)
        : "v"(b0p), "v"(b1p), "v"(b2p), "v"(b3p),
          "v"(b4p), "v"(b5p), "v"(b6p), "v"(b7p), "v"(sp0)
        : "memory");
    }
#pragma unroll
    for (int ks = 0; ks < 16; ++ks) {
      acc[0][0] = __builtin_amdgcn_mfma_f32_16x16x32_bf16(ha[ks][0], u_frag[ks][0], acc[0][0], 0, 0, 0);
      acc[0][1] = __builtin_amdgcn_mfma_f32_16x16x32_bf16(ha[ks][0], u_frag[ks][1], acc[0][1], 0, 0, 0);
      acc[1][0] = __builtin_amdgcn_mfma_f32_16x16x32_bf16(ha[ks][1], u_frag[ks][0], acc[1][0], 0, 0, 0);
      acc[1][1] = __builtin_amdgcn_mfma_f32_16x16x32_bf16(ha[ks][1], u_frag[ks][1], acc[1][1], 0, 0, 0);
    }
  }

  // ---- regroup gates per (b,u) via LDS ----
#pragma unroll
  for (int ms = 0; ms < 2; ++ms)
#pragma unroll
    for (int ns = 0; ns < 2; ++ns)
#pragma unroll
      for (int r = 0; r < 4; ++r)
        Z[mh * 32 + ms * 16 + l4 * 4 + r][nh * 32 + ns * 16 + l15] = acc[ms][ns][r];
  __syncthreads();

  // ---- cell + masked carry: thread = (batch eb, 4 units uq*4..+3) ----
  f32x4 vi = *(const f32x4*)&Z[eb][uq * 4];
  f32x4 vf = *(const f32x4*)&Z[eb][16 + uq * 4];
  f32x4 vg = *(const f32x4*)&Z[eb][32 + uq * 4];
  f32x4 vo = *(const f32x4*)&Z[eb][48 + uq * 4];
  float hv[4], cv[4];
  {
    const bool m = (msk != 0);
    float hi_[4] = {hin0[0], hin0[2], hin1[0], hin1[2]};
    float ci_[4] = {hin0[1], hin0[3], hin1[1], hin1[3]};
#pragma unroll
    for (int i = 0; i < 4; ++i) {
      float ig = sigm(vi[i] + bias[0][i]);
      float fg = sigm(vf[i] + bias[1][i]);
      float gg = tanh_(vg[i] + bias[2][i]);
      float og = sigm(vo[i] + bias[3][i]);
      float cn = fg * ci_[i] + ig * gg;
      float hn = og * tanh_(cn);
      hv[i] = m ? hn : hi_[i];
      cv[i] = m ? cn : ci_[i];
    }
  }

  // ---- publish H(s+1) bf16 (1x dwordx2) + (h,c) state (2x dwordx4):
  //      coalesced block-owned lines, ONE drain ----
  {
    u32x2 hu;
    hu[0] = (unsigned)f2bf(hv[0]) | ((unsigned)f2bf(hv[1]) << 16);
    hu[1] = (unsigned)f2bf(hv[2]) | ((unsigned)f2bf(hv[3]) << 16);
    f32x4 sc0v, sc1v;
    sc0v[0] = hv[0]; sc0v[1] = cv[0]; sc0v[2] = hv[1]; sc0v[3] = cv[1];
    sc1v[0] = hv[2]; sc1v[1] = cv[2]; sc1v[2] = hv[3]; sc1v[3] = cv[3];
    char* hp = (char*)(Hst + ((size_t)((s + 1) & 1) * 2 + d) * 32768
                       + (size_t)cg * 1024 + eb * 16 + uq * 4);
    char* scp = (char*)(SC + ((size_t)((s + 1) & 1) * 2 + d) * 32768
                        + (size_t)cg * 1024 + eb * 16 + uq * 4);
    asm volatile(
      "global_store_dwordx2 %0, %2, off sc0 sc1\n\t"
      "global_store_dwordx4 %1, %3, off sc0 sc1\n\t"
      "global_store_dwordx4 %1, %4, off offset:16 sc0 sc1\n\t"
      "s_waitcnt vmcnt(0)"
      :: "v"(hp), "v"(scp), "v"(hu), "v"(sc0v), "v"(sc1v)
      : "memory");
  }
  __syncthreads();   // all waves' publishes drained before the flag
  if (tid == 0)
    __hip_atomic_store(flg + ((size_t)(s + 1) * 2 + d) * 32 + cg, 1,
                       __ATOMIC_RELAXED, __HIP_MEMORY_SCOPE_AGENT);
  __builtin_amdgcn_s_setprio(0);

  // ---- out stores (HBM, off the dependency chain, dwordx4) ----
  {
    f32x4 ov, cvv;
#pragma unroll
    for (int i = 0; i < 4; ++i) { ov[i] = hv[i]; cvv[i] = cv[i]; }
    *(f32x4*)&out[((size_t)eb * T_ + t) * 1024 + d * 512 + u0 + uq * 4] = ov;
    if (s == T_ - 1) {
      *(f32x4*)&out[33554432u + (size_t)eb * 1024 + d * 512 + u0 + uq * 4] = ov;
      *(f32x4*)&out[33619968u + (size_t)eb * 1024 + d * 512 + u0 + uq * 4] = cvv;
    }
  }
}

// ---------------- R8 fallback: step-per-launch (verbatim, proven) ----------
__global__ __launch_bounds__(256, 1)
void lstm_step(const int s, const int* __restrict__ enc, const unsigned short* __restrict__ embq,
               const unsigned short* __restrict__ Uq, const unsigned short* __restrict__ Wq,
               const float* __restrict__ bfv, const float* __restrict__ bbv,
               unsigned short* __restrict__ Hbf, float* __restrict__ Hf32,
               float* __restrict__ Cst, float* __restrict__ out) {
  const int tid = threadIdx.x;
  const int lane = tid & 63;
  const int wave = tid >> 6;
  const int mh = wave & 1, nh = wave >> 1;
  const int l15 = lane & 15, l4 = lane >> 4;
  const int d = blockIdx.x >> 5;
  const int cg = blockIdx.x & 31;
  const int u0 = cg * 16;
  const int t = d ? (T_ - 1 - s) : s;

  __shared__ float Z[64][68];

  const unsigned short* ub = Uq + ((size_t)((d * 32 + cg) * 2 + nh)) * (16 * 2 * 512);
  const unsigned short* wb = Wq + ((size_t)((d * 32 + cg) * 2 + nh)) * (8 * 2 * 512);
  bf16x8 u_frag[16][2];
#pragma unroll
  for (int ks = 0; ks < 16; ++ks)
#pragma unroll
    for (int ns = 0; ns < 2; ++ns)
      u_frag[ks][ns] = *(const bf16x8*)(ub + (size_t)(ks * 2 + ns) * 512 + lane * 8);
  bf16x8 w_frag[8][2];
#pragma unroll
  for (int ks = 0; ks < 8; ++ks)
#pragma unroll
    for (int ns = 0; ns < 2; ++ns)
      w_frag[ks][ns] = *(const bf16x8*)(wb + (size_t)(ks * 2 + ns) * 512 + lane * 8);

  bf16x8 apf[8][2];
  {
    const unsigned short* eT = embq + (size_t)t * (B_ * E_);
#pragma unroll
    for (int ks = 0; ks < 8; ++ks)
#pragma unroll
      for (int ms = 0; ms < 2; ++ms) {
        const int b = mh * 32 + ms * 16 + l15;
        apf[ks][ms] = *(const bf16x8*)(eT + b * E_ + ks * 32 + l4 * 8);
      }
  }
  const int ej = tid & 15;
  const int ebg = tid >> 4;
  int mpf[4];
#pragma unroll
  for (int r = 0; r < 4; ++r) mpf[r] = enc[(ebg * 4 + r) * T_ + t];

  f32x4 acc[2][2];
#pragma unroll
  for (int ms = 0; ms < 2; ++ms)
#pragma unroll
    for (int ns = 0; ns < 2; ++ns) acc[ms][ns] = (f32x4)0.0f;

#pragma unroll
  for (int ks = 0; ks < 8; ++ks)
#pragma unroll
    for (int ms = 0; ms < 2; ++ms)
#pragma unroll
      for (int ns = 0; ns < 2; ++ns)
        acc[ms][ns] = __builtin_amdgcn_mfma_f32_16x16x32_bf16(apf[ks][ms], w_frag[ks][ns],
                                                              acc[ms][ns], 0, 0, 0);

  if (s > 0) {
    const unsigned short* Hrd = Hbf + ((size_t)((s & 1) * 2 + d)) * (B_ * 512);
    bf16x8 ha[16][2];
#pragma unroll
    for (int ks = 0; ks < 16; ++ks)
#pragma unroll
      for (int ms = 0; ms < 2; ++ms) {
        const int b = mh * 32 + ms * 16 + l15;
        ha[ks][ms] = *(const bf16x8*)(Hrd + (size_t)b * 512 + ks * 32 + l4 * 8);
      }
#pragma unroll
    for (int ks = 0; ks < 16; ++ks) {
      acc[0][0] = __builtin_amdgcn_mfma_f32_16x16x32_bf16(ha[ks][0], u_frag[ks][0], acc[0][0], 0, 0, 0);
      acc[0][1] = __builtin_amdgcn_mfma_f32_16x16x32_bf16(ha[ks][0], u_frag[ks][1], acc[0][1], 0, 0, 0);
      acc[1][0] = __builtin_amdgcn_mfma_f32_16x16x32_bf16(ha[ks][1], u_frag[ks][0], acc[1][0], 0, 0, 0);
      acc[1][1] = __builtin_amdgcn_mfma_f32_16x16x32_bf16(ha[ks][1], u_frag[ks][1], acc[1][1], 0, 0, 0);
    }
  }

#pragma unroll
  for (int ms = 0; ms < 2; ++ms)
#pragma unroll
    for (int ns = 0; ns < 2; ++ns)
#pragma unroll
      for (int r = 0; r < 4; ++r)
        Z[mh * 32 + ms * 16 + l4 * 4 + r][nh * 32 + ns * 16 + l15] = acc[ms][ns][r];
  __syncthreads();

  const float* bd = d ? bbv : bfv;
  float bias[4];
#pragma unroll
  for (int g = 0; g < 4; ++g) bias[g] = bd[g * 512 + u0 + ej];

  float* Hf = Hf32 + (size_t)d * (B_ * 512);
  float* Cf = Cst + (size_t)d * (B_ * 512);
  unsigned short* Hwr = Hbf + ((size_t)(((s + 1) & 1) * 2 + d)) * (B_ * 512);
  const bool last = (s == T_ - 1);
#pragma unroll
  for (int r = 0; r < 4; ++r) {
    const int b = ebg * 4 + r;
    const size_t si = (size_t)b * 512 + u0 + ej;
    float zi = Z[b][ej] + bias[0];
    float zf = Z[b][16 + ej] + bias[1];
    float zg = Z[b][32 + ej] + bias[2];
    float zo = Z[b][48 + ej] + bias[3];
    float ig = sigm(zi), fg = sigm(zf), gg = tanh_(zg), og = sigm(zo);
    float hp = Hf[si], cp = Cf[si];
    float cn = fg * cp + ig * gg;
    float hn = og * tanh_(cn);
    const bool m = (mpf[r] != 0);
    float hv = m ? hn : hp;
    float cv = m ? cn : cp;
    Hf[si] = hv;
    Cf[si] = cv;
    Hwr[si] = f2bf(hv);
    out[((size_t)b * T_ + t) * 1024 + d * 512 + u0 + ej] = hv;
    if (last) {
      out[33554432u + (size_t)b * 1024 + d * 512 + u0 + ej] = hv;
      out[33619968u + (size_t)b * 1024 + d * 512 + u0 + ej] = cv;
    }
  }
}

extern "C" void kernel_launch(void* const* d_in, const int* in_sizes, int n_in,
                              void* d_out, int out_size, void* d_ws, size_t ws_size,
                              hipStream_t stream) {
  const int* enc = (const int*)d_in[0];
  const float* emb = (const float*)d_in[1];
  const float* Wf = (const float*)d_in[2];
  const float* Uf = (const float*)d_in[3];
  const float* bf = (const float*)d_in[4];
  const float* Wb = (const float*)d_in[5];
  const float* Ub = (const float*)d_in[6];
  const float* bb = (const float*)d_in[7];
  float* out = (float*)d_out;
  char* ws = (char*)d_ws;

  // shared prep regions
  unsigned short* embq = (unsigned short*)ws;                  // 16 MiB
  unsigned short* Uq  = (unsigned short*)(ws + 16777216u);     // 4 MiB
  unsigned short* Wq  = (unsigned short*)(ws + 20971520u);     // 2 MiB

  // primary (DAG) layout: 25.6 MB total
  const size_t OFF_HST = 23068672u;                            // [2][2][32][64][16] bf16, 256 KiB
  const size_t OFF_SC  = 23330816u;                            // [2][2][32][64][16] float2, 2 MiB
  const size_t OFF_FLG = 25427968u;                            // [513][2][32] int
  const size_t NEED    = 25559296u;

  prep_kernel<<<32768, 64, 0, stream>>>(enc, emb, embq);
  prep_w<<<6144, 64, 0, stream>>>(Wf, Uf, Wb, Ub, Uq, Wq);

  if (ws_size >= NEED) {
    unsigned short* Hst = (unsigned short*)(ws + OFF_HST);
    f32x2* SC = (f32x2*)(ws + OFF_SC);
    int*   flg = (int*)(ws + OFF_FLG);
    hipMemsetAsync(ws + OFF_SC, 0, NEED - OFF_SC, stream);
    lstm_dag<<<32768, 256, 0, stream>>>(enc, embq, Uq, Wq, bf, bb,
                                        Hst, SC, flg, out);
  } else {
    // fallback: verbatim R8 step-per-launch (proven pass at 7037 us)
    unsigned short* Hbf = (unsigned short*)(ws + 23068672u);
    float* Hf32 = (float*)(ws + 23330816u);
    float* Cst  = (float*)(ws + 23592960u);
    hipMemsetAsync(ws + 23068672u, 0, 786432u, stream);
    for (int s = 0; s < 512; ++s)
      lstm_step<<<64, 256, 0, stream>>>(s, enc, embq, Uq, Wq, bf, bb, Hbf, Hf32, Cst, out);
  }
}